// Round 6
// baseline (194.162 us; speedup 1.0000x reference)
//
#include <hip/hip_runtime.h>

#define VOCAB 40
#define SEQ 128
#define THREADS 256          // 1 thread = 1 row; block = 256 rows
#define RSTRIDE 36           // staging tile row stride (words): 32 tokens + 4 pad
#define NW 10                // 10 byte-packed hist words per thread (40 bins)

// Histogram layout: COLUMN-MAJOR hist[word][tid]. Thread tid's counters all
// sit at byte addr ≡ tid*4 (mod 128) -> bank = tid%32 for EVERY token value.
// A wave's 64 lanes therefore always hit 32 banks with exactly 2 lanes/bank
// (different addresses), which is measured-free on gfx950 (m136: 1.02x).

__global__ __launch_bounds__(THREADS) void char_dist_kernel(
    const int* __restrict__ x, float* __restrict__ out, int batch) {
  __shared__ unsigned int tile[THREADS * RSTRIDE];   // 36864 B
  __shared__ unsigned int hist[NW * THREADS];        // 10240 B col-major
  const int tid = threadIdx.x;
  const int rowBase = blockIdx.x * THREADS;

  unsigned int* hb = &hist[tid];  // this thread's column
#pragma unroll
  for (int w = 0; w < NW; ++w) hb[w * THREADS] = 0u;

  // ---- staging geometry (unchanged from r5, proven HBM-minimal) ----
  // chunk c (0..3) covers tokens [32c, 32c+32) of all 256 rows.
  // instr k (0..7): thread i handles row k*32 + (i>>3), 16B-block (i&7).
  const int lrow = tid >> 3;           // 0..31
  const int lblk = tid & 7;            // 0..7
  const int4* gbase = reinterpret_cast<const int4*>(x);

#define LOAD_CHUNK(R, c)                                                     \
  _Pragma("unroll") for (int k = 0; k < 8; ++k) {                            \
    const int r = k * 32 + lrow;                                             \
    const long grow = (long)(rowBase + r);                                   \
    (R)[k] = (grow < batch) ? gbase[grow * 32 + (c) * 8 + lblk]              \
                            : make_int4(0, 0, 0, 0);                         \
  }

#define STORE_CHUNK(R)                                                       \
  _Pragma("unroll") for (int k = 0; k < 8; ++k) {                            \
    const int r = k * 32 + lrow;                                             \
    *reinterpret_cast<int4*>(&tile[r * RSTRIDE + lblk * 4]) = (R)[k];        \
  }

// hist RMW: word index (t>>2) scaled by THREADS; byte-packed increment.
#define HADD(t)                                                              \
  hb[((t) >> 2) * THREADS] += 1u << (((t) & 3) << 3);

#define PROC_CHUNK()                                                         \
  _Pragma("unroll") for (int k = 0; k < 8; ++k) {                            \
    const int4 t4 =                                                          \
        *reinterpret_cast<const int4*>(&tile[tid * RSTRIDE + k * 4]);        \
    HADD(t4.x) HADD(t4.y) HADD(t4.z) HADD(t4.w)                              \
  }

  int4 A[8], B[8];
  LOAD_CHUNK(A, 0)
  // c = 0
  LOAD_CHUNK(B, 1)
  STORE_CHUNK(A)
  __syncthreads();
  PROC_CHUNK()
  __syncthreads();
  // c = 1
  LOAD_CHUNK(A, 2)
  STORE_CHUNK(B)
  __syncthreads();
  PROC_CHUNK()
  __syncthreads();
  // c = 2
  LOAD_CHUNK(B, 3)
  STORE_CHUNK(A)
  __syncthreads();
  PROC_CHUNK()
  __syncthreads();
  // c = 3
  STORE_CHUNK(B)
  __syncthreads();
  PROC_CHUNK()

  // ---- epilogue: unpack own 40-bin byte-packed histogram ----
  const int row = rowBase + tid;
  if (row >= batch) return;

  int total = 0, uniq = 0, maxc = 0, minc = 0x7fffffff;
  int letters = 0, digits = 0, special = 0;
#pragma unroll
  for (int w = 0; w < NW; ++w) {
    const unsigned int m = hb[w * THREADS];
#pragma unroll
    for (int b = 0; b < 4; ++b) {
      const int bin = w * 4 + b;
      const int c = (int)((m >> (b * 8)) & 0xFFu);
      if (bin != 0) {  // bin 0 is padding, excluded from all stats
        total += c;
        uniq += (c > 0) ? 1 : 0;
        maxc = max(maxc, c);
        if (c > 0) minc = min(minc, c);
        if (bin <= 26) letters += c;
        else if (bin <= 36) digits += c;
        else special += c;
      }
    }
  }

  float f0, f1, f2, f3, f4, f5;
  if (total > 0) {
    const float inv = 1.0f / (float)total;
    f0 = (float)uniq * (1.0f / (float)VOCAB);
    f1 = (float)maxc * inv;
    f2 = (float)minc * inv;
    f3 = (float)letters * inv;
    f4 = (float)digits * inv;
    f5 = (float)special * inv;
  } else {
    f0 = f1 = f2 = f3 = f4 = f5 = 0.0f;
  }
  float2* o = reinterpret_cast<float2*>(out + (long)row * 6);
  o[0] = make_float2(f0, f1);
  o[1] = make_float2(f2, f3);
  o[2] = make_float2(f4, f5);
}

extern "C" void kernel_launch(void* const* d_in, const int* in_sizes, int n_in,
                              void* d_out, int out_size, void* d_ws, size_t ws_size,
                              hipStream_t stream) {
  const int* x = (const int*)d_in[0];
  float* out = (float*)d_out;
  const int batch = in_sizes[0] / SEQ;
  const int blocks = (batch + THREADS - 1) / THREADS;
  char_dist_kernel<<<blocks, THREADS, 0, stream>>>(x, out, batch);
}